// Round 1
// baseline (1199.460 us; speedup 1.0000x reference)
//
#include <hip/hip_runtime.h>
#include <math.h>

// Problem constants (fixed by setup_inputs)
#define BATCH 2
#define DIM   256
#define THW   8192            // T*H*W = 8*32*32
#define NTOK  16384           // BATCH*THW
#define KCB   8192            // codebook size
#define OUTQ  4194304         // BATCH*DIM*THW

// ---------------------------------------------------------------------------
// Kernel 0: transpose z [B][D][THW] -> z_tt [D][NTOK] (n = b*THW+thw), + zsq[n]
// zsq accumulated in double to minimize noise vs reference.
// ---------------------------------------------------------------------------
__global__ void k_ztrans(const float* __restrict__ z, float* __restrict__ z_tt,
                         float* __restrict__ zsq) {
    int blk = blockIdx.x;          // 64 blocks
    int b   = blk >> 5;            // 0..1
    int c0  = (blk & 31) * 256;    // thw chunk
    int t   = threadIdx.x;         // 256 threads
    int thw = c0 + t;
    int n   = b * THW + thw;
    const float* zb = z + (size_t)b * DIM * THW;
    double acc = 0.0;
    for (int d = 0; d < DIM; d += 4) {
        float v0 = zb[(size_t)(d + 0) * THW + thw];
        float v1 = zb[(size_t)(d + 1) * THW + thw];
        float v2 = zb[(size_t)(d + 2) * THW + thw];
        float v3 = zb[(size_t)(d + 3) * THW + thw];
        z_tt[(size_t)(d + 0) * NTOK + n] = v0;
        z_tt[(size_t)(d + 1) * NTOK + n] = v1;
        z_tt[(size_t)(d + 2) * NTOK + n] = v2;
        z_tt[(size_t)(d + 3) * NTOK + n] = v3;
        acc += (double)v0 * v0 + (double)v1 * v1 + (double)v2 * v2 + (double)v3 * v3;
    }
    zsq[n] = (float)acc;
}

// ---------------------------------------------------------------------------
// Generic 32x32 tile transpose: in [rows][cols] -> out [cols][rows]
// ---------------------------------------------------------------------------
__global__ void k_transpose(const float* __restrict__ in, float* __restrict__ out,
                            int rows, int cols) {
    __shared__ float tile[32][33];
    int tx = threadIdx.x, ty = threadIdx.y;   // 32 x 8
    int x  = blockIdx.x * 32 + tx;
    int y0 = blockIdx.y * 32;
    for (int j = ty; j < 32; j += 8)
        tile[j][tx] = in[(size_t)(y0 + j) * cols + x];
    __syncthreads();
    int x2 = y0 + tx;
    int y2 = blockIdx.x * 32;
    for (int j = ty; j < 32; j += 8)
        out[(size_t)(y2 + j) * rows + x2] = tile[tx][j];
}

// ---------------------------------------------------------------------------
// MLP GEMM: Out[m][n] = act( sum_d At[d][m] * Bt[d][n] ),  D = 256.
// At: [256][M], Bt: [256][N], Out row-major [M][N].
// Double accumulation (exactness hedge: our codebook must be closer to the
// true value than the argmin tie grid). H rounded to fp32 BEFORE gelu.
// BM=64, BN=128, BK=16, 512 threads, 4x4 per thread.
// ---------------------------------------------------------------------------
template <int GELU>
__global__ __launch_bounds__(512) void k_gemm_tt(const float* __restrict__ At,
                                                 const float* __restrict__ Bt,
                                                 float* __restrict__ Out,
                                                 int M, int N) {
    __shared__ float As[16][64];
    __shared__ float Bs[16][128];
    int t  = threadIdx.x;
    int ty = t >> 5;        // 0..15 -> rows ty*4..+3
    int tx = t & 31;        // 0..31 -> cols tx*4..+3
    int m0 = blockIdx.y * 64;
    int n0 = blockIdx.x * 128;
    double acc[4][4] = {};
    int dq = t >> 5;        // 0..15
    int lq = t & 31;        // 0..31
    for (int dc = 0; dc < 256; dc += 16) {
        *(float2*)&As[dq][lq * 2] = *(const float2*)&At[(size_t)(dc + dq) * M + m0 + lq * 2];
        *(float4*)&Bs[dq][lq * 4] = *(const float4*)&Bt[(size_t)(dc + dq) * N + n0 + lq * 4];
        __syncthreads();
#pragma unroll
        for (int di = 0; di < 16; ++di) {
            float4 a = *(const float4*)&As[di][ty * 4];
            float4 b = *(const float4*)&Bs[di][tx * 4];
            float av[4] = {a.x, a.y, a.z, a.w};
            float bv[4] = {b.x, b.y, b.z, b.w};
#pragma unroll
            for (int i = 0; i < 4; ++i)
#pragma unroll
                for (int j = 0; j < 4; ++j)
                    acc[i][j] += (double)av[i] * (double)bv[j];
        }
        __syncthreads();
    }
#pragma unroll
    for (int i = 0; i < 4; ++i) {
        float v[4];
#pragma unroll
        for (int j = 0; j < 4; ++j) {
            float h = (float)acc[i][j];   // round to fp32 first (matches ref H dtype)
            if (GELU) {
                double x = (double)h;
                h = (float)(x * 0.5 * (1.0 + erf(x * 0.7071067811865475244)));
            }
            v[j] = h;
        }
        *(float4*)&Out[(size_t)(m0 + ty * 4 + i) * N + n0 + tx * 4] =
            make_float4(v[0], v[1], v[2], v[3]);
    }
}

// ---------------------------------------------------------------------------
// csq[k] = sum_d C_t[d][k]^2  (double accumulation)
// ---------------------------------------------------------------------------
__global__ void k_csq(const float* __restrict__ C_t, float* __restrict__ csq) {
    int k = blockIdx.x * 256 + threadIdx.x;
    double acc = 0.0;
    for (int d = 0; d < DIM; ++d) {
        float v = C_t[(size_t)d * KCB + k];
        acc += (double)v * v;
    }
    csq[k] = (float)acc;
}

// ---------------------------------------------------------------------------
// Main distance kernel: for 64 rows x 2048-k slice, compute
//   d = (zsq[n] + csq[k]) - 2*dot(z_n, c_k)     (exact ref rounding order)
// track lexicographic argmin (first index on ties), accumulate sum(d).
// grid (256 m-tiles, 4 k-splits), 512 threads, 4x4 per thread, BN=128, BK=16.
// ---------------------------------------------------------------------------
__global__ __launch_bounds__(512) void k_dist(const float* __restrict__ z_tt,
                                              const float* __restrict__ C_t,
                                              const float* __restrict__ zsq,
                                              const float* __restrict__ csq,
                                              unsigned long long* __restrict__ packed,
                                              float* __restrict__ d_sum) {
    __shared__ float As[16][64];
    __shared__ float Bs[16][128];
    __shared__ float zsq_s[64];
    __shared__ float best_d[64];
    __shared__ int   best_k[64];
    __shared__ float red[512];
    int t  = threadIdx.x;
    int ty = t >> 5;         // 0..15
    int tx = t & 31;         // 0..31
    int m0 = blockIdx.x * 64;
    int kbase = blockIdx.y * 2048;
    if (t < 64) {
        zsq_s[t]  = zsq[m0 + t];
        best_d[t] = 3.4e38f;
        best_k[t] = 0;
    }
    __syncthreads();
    float dsum = 0.f;
    int dq = t >> 5, lq = t & 31;
    for (int kt = 0; kt < 16; ++kt) {
        int k0 = kbase + kt * 128;
        float acc[4][4] = {};
        for (int dc = 0; dc < 256; dc += 16) {
            *(float2*)&As[dq][lq * 2] = *(const float2*)&z_tt[(size_t)(dc + dq) * NTOK + m0 + lq * 2];
            *(float4*)&Bs[dq][lq * 4] = *(const float4*)&C_t[(size_t)(dc + dq) * KCB + k0 + lq * 4];
            __syncthreads();
#pragma unroll
            for (int di = 0; di < 16; ++di) {
                float4 a = *(const float4*)&As[di][ty * 4];
                float4 b = *(const float4*)&Bs[di][tx * 4];
                float av[4] = {a.x, a.y, a.z, a.w};
                float bv[4] = {b.x, b.y, b.z, b.w};
#pragma unroll
                for (int i = 0; i < 4; ++i)
#pragma unroll
                    for (int j = 0; j < 4; ++j)
                        acc[i][j] += av[i] * bv[j];
            }
            __syncthreads();
        }
        // epilogue: distances + running argmin (reads only regs/zsq_s/best arrays)
        float4 cq = *(const float4*)&csq[k0 + tx * 4];
        float cv[4] = {cq.x, cq.y, cq.z, cq.w};
#pragma unroll
        for (int i = 0; i < 4; ++i) {
            float zs = zsq_s[ty * 4 + i];
            float dv[4];
#pragma unroll
            for (int j = 0; j < 4; ++j)
                dv[j] = (zs + cv[j]) - 2.0f * acc[i][j];
            dsum += (dv[0] + dv[1]) + (dv[2] + dv[3]);
            float bd = dv[0];
            int   bk = k0 + tx * 4;
            if (dv[1] < bd) { bd = dv[1]; bk = k0 + tx * 4 + 1; }
            if (dv[2] < bd) { bd = dv[2]; bk = k0 + tx * 4 + 2; }
            if (dv[3] < bd) { bd = dv[3]; bk = k0 + tx * 4 + 3; }
            // butterfly over the 32 tx lanes (xor masks <32 stay in-half)
#pragma unroll
            for (int off = 1; off < 32; off <<= 1) {
                float od = __shfl_xor(bd, off, 64);
                int   ok = __shfl_xor(bk, off, 64);
                if (od < bd || (od == bd && ok < bk)) { bd = od; bk = ok; }
            }
            if (tx == 0) {
                int row = ty * 4 + i;   // same owner thread every kt: no race
                if (bd < best_d[row]) { best_d[row] = bd; best_k[row] = bk; }
            }
        }
    }
    // sum(d) block reduction
    red[t] = dsum;
    __syncthreads();
    for (int s = 256; s > 0; s >>= 1) {
        if (t < s) red[t] += red[t + s];
        __syncthreads();
    }
    if (t == 0) atomicAdd(d_sum, red[0]);
    // merge across k-split blocks: packed (d_bits<<32)|k, d>=0 so order-safe
    if (t < 64) {
        unsigned long long p =
            ((unsigned long long)__float_as_uint(best_d[t]) << 32) |
            (unsigned long long)(unsigned int)best_k[t];
        atomicMin(&packed[m0 + t], p);
    }
}

// ---------------------------------------------------------------------------
// Unpack argmin + histogram
// ---------------------------------------------------------------------------
__global__ void k_unpack(const unsigned long long* __restrict__ packed,
                         int* __restrict__ idx, int* __restrict__ counts) {
    int n = blockIdx.x * 256 + threadIdx.x;
    unsigned long long p = packed[n];
    int k = (int)(p & 0xffffffffull);
    idx[n] = k;
    atomicAdd(&counts[k], 1);
}

// ---------------------------------------------------------------------------
// z_q gather (channels-first layout, same as z) + loss partial sums
// grid: BATCH*DIM blocks, 256 threads
// ---------------------------------------------------------------------------
__global__ void k_zqloss(const float* __restrict__ z, const float* __restrict__ C_t,
                         const int* __restrict__ idx, float* __restrict__ out,
                         float* __restrict__ loss_sum) {
    __shared__ float red[256];
    int bid = blockIdx.x;
    int b = bid >> 8;
    int d = bid & 255;
    int t = threadIdx.x;
    const float* crow = C_t + (size_t)d * KCB;
    const int* ib = idx + b * THW;
    size_t base = ((size_t)(b * DIM + d)) * THW;
    float lsum = 0.f;
    for (int it = 0; it < 32; ++it) {
        int thw = it * 256 + t;
        int id = ib[thw];
        float v = crow[id];
        float zz = z[base + thw];
        out[base + thw] = v;
        float df = v - zz;
        lsum += df * df;
    }
    red[t] = lsum;
    __syncthreads();
    for (int s = 128; s > 0; s >>= 1) {
        if (t < s) red[t] += red[t + s];
        __syncthreads();
    }
    if (t == 0) atomicAdd(loss_sum, red[0]);
}

// ---------------------------------------------------------------------------
// Final scalars: loss, perplexity, mean_distance
// accums[0] = d_sum, accums[1] = loss_sum
// ---------------------------------------------------------------------------
__global__ void k_scalars(const int* __restrict__ counts,
                          const float* __restrict__ accums,
                          float* __restrict__ out_tail) {
    __shared__ float red[256];
    int t = threadIdx.x;
    float s = 0.f;
    for (int k = t; k < KCB; k += 256) {
        float e = (float)counts[k] * (1.0f / 16384.0f);
        s += e * logf(e + 1e-10f);
    }
    red[t] = s;
    __syncthreads();
    for (int st = 128; st > 0; st >>= 1) {
        if (t < st) red[t] += red[t + st];
        __syncthreads();
    }
    if (t == 0) {
        out_tail[0] = 1.25f * accums[1] / 4194304.0f;         // loss = (1+BETA)*mse
        out_tail[1] = expf(-red[0]);                          // perplexity
        out_tail[2] = accums[0] / (16384.0f * 8192.0f);       // mean_distance
    }
}

// ---------------------------------------------------------------------------
extern "C" void kernel_launch(void* const* d_in, const int* in_sizes, int n_in,
                              void* d_out, int out_size, void* d_ws, size_t ws_size,
                              hipStream_t stream) {
    const float* z     = (const float*)d_in[0];   // [2][256][8192]
    const float* emb_w = (const float*)d_in[1];   // [8192][256]
    const float* w1    = (const float*)d_in[2];   // [256][256]
    const float* w2    = (const float*)d_in[3];   // [256][256]
    float* out = (float*)d_out;

    char* w = (char*)d_ws;
    float* z_tt  = (float*)(w + 0);          // 16,777,216 B  [256][16384]
    float* emb_t = (float*)(w + 16777216);   //  8,388,608 B  [256][8192]
    float* H_t   = (float*)(w + 25165824);   //  8,388,608 B  [256][8192]
    float* C_t   = (float*)(w + 33554432);   //  8,388,608 B  [256][8192]
    float* w1t   = (float*)(w + 41943040);   //    262,144 B  [256][256]
    float* w2t   = (float*)(w + 42205184);   //    262,144 B
    float* zsq   = (float*)(w + 42467328);   //     65,536 B
    float* csq   = (float*)(w + 42532864);   //     32,768 B
    unsigned long long* packed = (unsigned long long*)(w + 42565632); // 131,072 B
    int*   idx    = (int*)(w + 42696704);    //     65,536 B
    int*   counts = (int*)(w + 42762240);    //     32,768 B
    float* accums = (float*)(w + 42795008);  // [0]=d_sum [1]=loss_sum

    // zero counts + accums (contiguous), set packed to all-ones (= +inf key)
    hipMemsetAsync(counts, 0, 32768 + 8, stream);
    hipMemsetAsync(packed, 0xFF, (size_t)NTOK * 8, stream);

    // transposes
    k_ztrans<<<64, 256, 0, stream>>>(z, z_tt, zsq);
    {
        dim3 blk(32, 8);
        k_transpose<<<dim3(DIM / 32, KCB / 32), blk, 0, stream>>>(emb_w, emb_t, KCB, DIM);
        k_transpose<<<dim3(DIM / 32, DIM / 32), blk, 0, stream>>>(w1, w1t, DIM, DIM);
        k_transpose<<<dim3(DIM / 32, DIM / 32), blk, 0, stream>>>(w2, w2t, DIM, DIM);
    }
    // codebook MLP: H_t = gelu(w1 @ emb^T) ; C_t = w2 @ H^T   (both [256][8192])
    k_gemm_tt<1><<<dim3(KCB / 128, DIM / 64), 512, 0, stream>>>(w1t, emb_t, H_t, DIM, KCB);
    k_gemm_tt<0><<<dim3(KCB / 128, DIM / 64), 512, 0, stream>>>(w2t, H_t, C_t, DIM, KCB);
    k_csq<<<KCB / 256, 256, 0, stream>>>(C_t, csq);

    // distances + argmin + sum(d)
    k_dist<<<dim3(NTOK / 64, 4), 512, 0, stream>>>(z_tt, C_t, zsq, csq, packed, accums);

    // unpack + histogram
    k_unpack<<<NTOK / 256, 256, 0, stream>>>(packed, idx, counts);

    // z_q gather + loss
    k_zqloss<<<BATCH * DIM, 256, 0, stream>>>(z, C_t, idx, out, accums + 1);

    // scalars
    k_scalars<<<1, 256, 0, stream>>>(counts, accums, out + OUTQ);
}

// Round 2
// 664.051 us; speedup vs baseline: 1.8063x; 1.8063x over previous
//
#include <hip/hip_runtime.h>
#include <math.h>

// Problem constants (fixed by setup_inputs)
#define BATCH 2
#define DIM   256
#define THW   8192            // T*H*W = 8*32*32
#define NTOK  16384           // BATCH*THW
#define KCB   8192            // codebook size
#define OUTQ  4194304         // BATCH*DIM*THW
#define K2    768             // split-bf16 concatenated K

typedef short short8 __attribute__((ext_vector_type(8)));
typedef float f32x4 __attribute__((ext_vector_type(4)));

// round-to-nearest-even float -> bf16 bits (no NaN/Inf in this data)
__device__ __forceinline__ unsigned short f2bf_rn(float v) {
    unsigned u = __float_as_uint(v);
    unsigned r = u + 0x7FFFu + ((u >> 16) & 1u);
    return (unsigned short)(r >> 16);
}

// async global->LDS, 16B per lane (lds dest must be wave-uniform base + lane*16)
__device__ __forceinline__ void gl2lds16(const unsigned short* g, unsigned short* l) {
    __builtin_amdgcn_global_load_lds(
        (const __attribute__((address_space(1))) void*)g,
        (__attribute__((address_space(3))) void*)l, 16, 0, 0);
}

// ---------------------------------------------------------------------------
// Build A' [NTOK][768] bf16 = [zhi | zhi | zlo] from z [B][D][THW]; also zsq.
// zsq order-noise is row-constant in d -> argmin-invariant (2% tol on mean_d).
// ---------------------------------------------------------------------------
__global__ void k_buildA(const float* __restrict__ z, unsigned short* __restrict__ A,
                         float* __restrict__ zsq) {
    __shared__ ushort2 tile[64][65];
    __shared__ float zacc[64];
    int t = threadIdx.x;
    int n0 = blockIdx.x * 64;
    int b = n0 >> 13;
    int thw0 = n0 & 8191;
    if (t < 64) zacc[t] = 0.f;
    __syncthreads();
    int nn_r = t & 63, dg = t >> 6;
    for (int dc = 0; dc < 256; dc += 64) {
        for (int r = 0; r < 16; ++r) {
            int dd = r * 4 + dg;
            float v = z[((size_t)(b * 256 + dc + dd)) * 8192 + thw0 + nn_r];
            unsigned short hb = f2bf_rn(v);
            float hf = __uint_as_float((unsigned)hb << 16);
            unsigned short lb = f2bf_rn(v - hf);
            tile[dd][nn_r] = make_ushort2(hb, lb);
            atomicAdd(&zacc[nn_r], v * v);
        }
        __syncthreads();
        int kk = t & 63, ng = t >> 6;
        for (int i2 = 0; i2 < 16; ++i2) {
            int nn = ng + i2 * 4;
            ushort2 hl = tile[kk][nn];
            size_t base = (size_t)(n0 + nn) * K2;
            A[base + dc + kk]       = hl.x;   // zhi
            A[base + 256 + dc + kk] = hl.x;   // zhi (pairs with clo)
            A[base + 512 + dc + kk] = hl.y;   // zlo (pairs with chi)
        }
        __syncthreads();
    }
    if (t < 64) zsq[n0 + t] = zacc[t];
}

// ---------------------------------------------------------------------------
// Build B' [KCB][768] bf16 = [chi | clo | chi] from C_t [D][KCB]
// ---------------------------------------------------------------------------
__global__ void k_buildB(const float* __restrict__ C_t, unsigned short* __restrict__ B) {
    __shared__ ushort2 tile[64][65];
    int t = threadIdx.x;
    int k0 = blockIdx.x * 64;
    int nn_r = t & 63, dg = t >> 6;
    for (int dc = 0; dc < 256; dc += 64) {
        for (int r = 0; r < 16; ++r) {
            int dd = r * 4 + dg;
            float v = C_t[(size_t)(dc + dd) * KCB + k0 + nn_r];
            unsigned short hb = f2bf_rn(v);
            float hf = __uint_as_float((unsigned)hb << 16);
            unsigned short lb = f2bf_rn(v - hf);
            tile[dd][nn_r] = make_ushort2(hb, lb);
        }
        __syncthreads();
        int kk = t & 63, ng = t >> 6;
        for (int i2 = 0; i2 < 16; ++i2) {
            int nn = ng + i2 * 4;
            ushort2 hl = tile[kk][nn];
            size_t base = (size_t)(k0 + nn) * K2;
            B[base + dc + kk]       = hl.x;   // chi
            B[base + 256 + dc + kk] = hl.y;   // clo
            B[base + 512 + dc + kk] = hl.x;   // chi
        }
        __syncthreads();
    }
}

// ---------------------------------------------------------------------------
// Generic 32x32 tile transpose: in [rows][cols] -> out [cols][rows]
// ---------------------------------------------------------------------------
__global__ void k_transpose(const float* __restrict__ in, float* __restrict__ out,
                            int rows, int cols) {
    __shared__ float tile[32][33];
    int tx = threadIdx.x, ty = threadIdx.y;   // 32 x 8
    int x  = blockIdx.x * 32 + tx;
    int y0 = blockIdx.y * 32;
    for (int j = ty; j < 32; j += 8)
        tile[j][tx] = in[(size_t)(y0 + j) * cols + x];
    __syncthreads();
    int x2 = y0 + tx;
    int y2 = blockIdx.x * 32;
    for (int j = ty; j < 32; j += 8)
        out[(size_t)(y2 + j) * rows + x2] = tile[tx][j];
}

// ---------------------------------------------------------------------------
// MLP GEMM (unchanged, double-acc): Out[m][n] = act(sum_d At[d][m]*Bt[d][n])
// ---------------------------------------------------------------------------
template <int GELU>
__global__ __launch_bounds__(512) void k_gemm_tt(const float* __restrict__ At,
                                                 const float* __restrict__ Bt,
                                                 float* __restrict__ Out,
                                                 int M, int N) {
    __shared__ float As[16][64];
    __shared__ float Bs[16][128];
    int t  = threadIdx.x;
    int ty = t >> 5;
    int tx = t & 31;
    int m0 = blockIdx.y * 64;
    int n0 = blockIdx.x * 128;
    double acc[4][4] = {};
    int dq = t >> 5;
    int lq = t & 31;
    for (int dc = 0; dc < 256; dc += 16) {
        *(float2*)&As[dq][lq * 2] = *(const float2*)&At[(size_t)(dc + dq) * M + m0 + lq * 2];
        *(float4*)&Bs[dq][lq * 4] = *(const float4*)&Bt[(size_t)(dc + dq) * N + n0 + lq * 4];
        __syncthreads();
#pragma unroll
        for (int di = 0; di < 16; ++di) {
            float4 a = *(const float4*)&As[di][ty * 4];
            float4 b = *(const float4*)&Bs[di][tx * 4];
            float av[4] = {a.x, a.y, a.z, a.w};
            float bv[4] = {b.x, b.y, b.z, b.w};
#pragma unroll
            for (int i = 0; i < 4; ++i)
#pragma unroll
                for (int j = 0; j < 4; ++j)
                    acc[i][j] += (double)av[i] * (double)bv[j];
        }
        __syncthreads();
    }
#pragma unroll
    for (int i = 0; i < 4; ++i) {
        float v[4];
#pragma unroll
        for (int j = 0; j < 4; ++j) {
            float h = (float)acc[i][j];
            if (GELU) {
                double x = (double)h;
                h = (float)(x * 0.5 * (1.0 + erf(x * 0.7071067811865475244)));
            }
            v[j] = h;
        }
        *(float4*)&Out[(size_t)(m0 + ty * 4 + i) * N + n0 + tx * 4] =
            make_float4(v[0], v[1], v[2], v[3]);
    }
}

// ---------------------------------------------------------------------------
// csq[k] = sum_d C_t[d][k]^2  (double accumulation)
// ---------------------------------------------------------------------------
__global__ void k_csq(const float* __restrict__ C_t, float* __restrict__ csq) {
    int k = blockIdx.x * 256 + threadIdx.x;
    double acc = 0.0;
    for (int d = 0; d < DIM; ++d) {
        float v = C_t[(size_t)d * KCB + k];
        acc += (double)v * v;
    }
    csq[k] = (float)acc;
}

// ---------------------------------------------------------------------------
// Distance GEMM on MFMA: A'[16384][768] x B'[8192][768]^T, 128x128 tiles,
// 4 waves x (4x4) mfma_f32_16x16x32_bf16 frags, global_load_lds staging.
// Epilogue: d = (zsq+csq) - 2*dot, per-row argmin (lex ties), sum(d).
// ---------------------------------------------------------------------------
__global__ __launch_bounds__(256) void k_dist2(const unsigned short* __restrict__ A,
                                               const unsigned short* __restrict__ B,
                                               const float* __restrict__ zsq,
                                               const float* __restrict__ csq,
                                               unsigned long long* __restrict__ packed,
                                               float* __restrict__ d_sum) {
    __shared__ unsigned short Asm[128 * 64];   // [m][k] rows of 64 bf16
    __shared__ unsigned short Bsm[128 * 64];   // [n][k]
    __shared__ float zrow[128];
    __shared__ float crow[128];
    __shared__ float sbd[2][128];
    __shared__ int   sbk[2][128];
    __shared__ float sred[256];

    int t = threadIdx.x;
    int lane = t & 63;
    int w = t >> 6;
    int wm = w >> 1, wn = w & 1;
    int m0 = blockIdx.y * 128;
    int n0 = blockIdx.x * 128;

    // staging addresses: wave w covers rows w*8+(lane>>3) + 32*i, 16B per lane
    int rA = w * 8 + (lane >> 3);
    int cA = (lane & 7) * 8;                 // ushort offset within 64-k slice
    const unsigned short* gA = A + (size_t)(m0 + rA) * K2 + cA;
    const unsigned short* gB = B + (size_t)(n0 + rA) * K2 + cA;
    unsigned short* lA = &Asm[rA * 64 + cA]; // == wave base + lane*8 ushorts
    unsigned short* lB = &Bsm[rA * 64 + cA];

    if (t < 128) { zrow[t] = zsq[m0 + t]; crow[t] = csq[n0 + t]; }

    f32x4 acc[4][4];
#pragma unroll
    for (int i = 0; i < 4; ++i)
#pragma unroll
        for (int j = 0; j < 4; ++j)
            acc[i][j] = f32x4{0.f, 0.f, 0.f, 0.f};

    // prologue: stage kc=0
#pragma unroll
    for (int i = 0; i < 4; ++i) {
        gl2lds16(gA + (size_t)(32 * i) * K2, lA + 32 * i * 64);
        gl2lds16(gB + (size_t)(32 * i) * K2, lB + 32 * i * 64);
    }
    __syncthreads();

    int l15 = lane & 15;
    int quad = lane >> 4;
    for (int kc = 0; kc < 12; ++kc) {
#pragma unroll
        for (int kk = 0; kk < 2; ++kk) {
            short8 a[4], b[4];
#pragma unroll
            for (int i = 0; i < 4; ++i)
                a[i] = *(const short8*)&Asm[(wm * 64 + i * 16 + l15) * 64 + kk * 32 + quad * 8];
#pragma unroll
            for (int j = 0; j < 4; ++j)
                b[j] = *(const short8*)&Bsm[(wn * 64 + j * 16 + l15) * 64 + kk * 32 + quad * 8];
#pragma unroll
            for (int i = 0; i < 4; ++i)
#pragma unroll
                for (int j = 0; j < 4; ++j)
                    acc[i][j] = __builtin_amdgcn_mfma_f32_16x16x32_bf16(a[i], b[j], acc[i][j], 0, 0, 0);
        }
        __syncthreads();
        if (kc < 11) {
            int ko = (kc + 1) * 64;
#pragma unroll
            for (int i = 0; i < 4; ++i) {
                gl2lds16(gA + (size_t)(32 * i) * K2 + ko, lA + 32 * i * 64);
                gl2lds16(gB + (size_t)(32 * i) * K2 + ko, lB + 32 * i * 64);
            }
            __syncthreads();
        }
    }

    // epilogue: C/D layout col=lane&15, row=quad*4+reg
    float dsum = 0.f;
#pragma unroll
    for (int i = 0; i < 4; ++i) {
#pragma unroll
        for (int reg = 0; reg < 4; ++reg) {
            int rloc = wm * 64 + i * 16 + quad * 4 + reg;
            float zs = zrow[rloc];
            float bd = 3.4e38f;
            int   bk = 0x7fffffff;
#pragma unroll
            for (int j = 0; j < 4; ++j) {
                int cloc = wn * 64 + j * 16 + l15;
                float dd = (zs + crow[cloc]) - 2.0f * acc[i][j][reg];
                dsum += dd;
                int ck = n0 + cloc;
                if (dd < bd || (dd == bd && ck < bk)) { bd = dd; bk = ck; }
            }
#pragma unroll
            for (int off = 1; off < 16; off <<= 1) {
                float od = __shfl_xor(bd, off, 64);
                int   ok = __shfl_xor(bk, off, 64);
                if (od < bd || (od == bd && ok < bk)) { bd = od; bk = ok; }
            }
            if (l15 == 0) { sbd[wn][rloc] = bd; sbk[wn][rloc] = bk; }
        }
    }
    sred[t] = dsum;
    __syncthreads();
    for (int s = 128; s > 0; s >>= 1) {
        if (t < s) sred[t] += sred[t + s];
        __syncthreads();
    }
    if (t == 0) atomicAdd(d_sum, sred[0]);
    if (t < 128) {
        float d0 = sbd[0][t], d1 = sbd[1][t];
        int   i0 = sbk[0][t], i1 = sbk[1][t];
        float bd; int bk;
        if (d1 < d0 || (d1 == d0 && i1 < i0)) { bd = d1; bk = i1; }
        else                                  { bd = d0; bk = i0; }
        unsigned long long p =
            ((unsigned long long)__float_as_uint(bd) << 32) | (unsigned)bk;
        atomicMin(&packed[m0 + t], p);
    }
}

// ---------------------------------------------------------------------------
// Unpack argmin + histogram
// ---------------------------------------------------------------------------
__global__ void k_unpack(const unsigned long long* __restrict__ packed,
                         int* __restrict__ idx, int* __restrict__ counts) {
    int n = blockIdx.x * 256 + threadIdx.x;
    unsigned long long p = packed[n];
    int k = (int)(p & 0xffffffffull);
    idx[n] = k;
    atomicAdd(&counts[k], 1);
}

// ---------------------------------------------------------------------------
// z_q gather (channels-first) + loss partial sums
// ---------------------------------------------------------------------------
__global__ void k_zqloss(const float* __restrict__ z, const float* __restrict__ C_t,
                         const int* __restrict__ idx, float* __restrict__ out,
                         float* __restrict__ loss_sum) {
    __shared__ float red[256];
    int bid = blockIdx.x;
    int b = bid >> 8;
    int d = bid & 255;
    int t = threadIdx.x;
    const float* crow = C_t + (size_t)d * KCB;
    const int* ib = idx + b * THW;
    size_t base = ((size_t)(b * DIM + d)) * THW;
    float lsum = 0.f;
    for (int it = 0; it < 32; ++it) {
        int thw = it * 256 + t;
        int id = ib[thw];
        float v = crow[id];
        float zz = z[base + thw];
        out[base + thw] = v;
        float df = v - zz;
        lsum += df * df;
    }
    red[t] = lsum;
    __syncthreads();
    for (int s = 128; s > 0; s >>= 1) {
        if (t < s) red[t] += red[t + s];
        __syncthreads();
    }
    if (t == 0) atomicAdd(loss_sum, red[0]);
}

// ---------------------------------------------------------------------------
// Final scalars
// ---------------------------------------------------------------------------
__global__ void k_scalars(const int* __restrict__ counts,
                          const float* __restrict__ accums,
                          float* __restrict__ out_tail) {
    __shared__ float red[256];
    int t = threadIdx.x;
    float s = 0.f;
    for (int k = t; k < KCB; k += 256) {
        float e = (float)counts[k] * (1.0f / 16384.0f);
        s += e * logf(e + 1e-10f);
    }
    red[t] = s;
    __syncthreads();
    for (int st = 128; st > 0; st >>= 1) {
        if (t < st) red[t] += red[t + st];
        __syncthreads();
    }
    if (t == 0) {
        out_tail[0] = 1.25f * accums[1] / 4194304.0f;
        out_tail[1] = expf(-red[0]);
        out_tail[2] = accums[0] / (16384.0f * 8192.0f);
    }
}

// ---------------------------------------------------------------------------
extern "C" void kernel_launch(void* const* d_in, const int* in_sizes, int n_in,
                              void* d_out, int out_size, void* d_ws, size_t ws_size,
                              hipStream_t stream) {
    const float* z     = (const float*)d_in[0];   // [2][256][8192]
    const float* emb_w = (const float*)d_in[1];   // [8192][256]
    const float* w1    = (const float*)d_in[2];   // [256][256]
    const float* w2    = (const float*)d_in[3];   // [256][256]
    float* out = (float*)d_out;

    char* w = (char*)d_ws;
    unsigned short* Abf = (unsigned short*)(w + 0);          // 25,165,824 B [16384][768]
    float* R1    = (float*)(w + 25165824);   // emb_t, later aliased by C_t (8,388,608 B)
    float* H_t   = (float*)(w + 33554432);   // 8,388,608 B  [256][8192]
    float* w1t   = (float*)(w + 41943040);   // 262,144 B
    float* w2t   = (float*)(w + 42205184);   // 262,144 B
    float* zsq   = (float*)(w + 42467328);   // 65,536 B
    float* csq   = (float*)(w + 42532864);   // 32,768 B
    unsigned long long* packed = (unsigned long long*)(w + 42565632); // 131,072 B
    int*   idx    = (int*)(w + 42696704);    // 65,536 B
    int*   counts = (int*)(w + 42762240);    // 32,768 B
    float* accums = (float*)(w + 42795008);  // [0]=d_sum [1]=loss_sum

    float* emb_t = R1;
    float* C_t   = R1;                        // alias: emb_t dead after gemm#1
    // B' lives in d_out: dead before k_zqloss overwrites it with z_q
    unsigned short* Bbf = (unsigned short*)d_out;  // 12,582,912 B <= 16 MB

    hipMemsetAsync(counts, 0, 32768 + 8, stream);
    hipMemsetAsync(packed, 0xFF, (size_t)NTOK * 8, stream);

    // A' + zsq straight from z
    k_buildA<<<NTOK / 64, 256, 0, stream>>>(z, Abf, zsq);

    // transposes for the MLP GEMMs
    {
        dim3 blk(32, 8);
        k_transpose<<<dim3(DIM / 32, KCB / 32), blk, 0, stream>>>(emb_w, emb_t, KCB, DIM);
        k_transpose<<<dim3(DIM / 32, DIM / 32), blk, 0, stream>>>(w1, w1t, DIM, DIM);
        k_transpose<<<dim3(DIM / 32, DIM / 32), blk, 0, stream>>>(w2, w2t, DIM, DIM);
    }
    // codebook MLP: H_t = gelu(w1 @ emb^T) ; C_t = w2 @ H^T
    k_gemm_tt<1><<<dim3(KCB / 128, DIM / 64), 512, 0, stream>>>(w1t, emb_t, H_t, DIM, KCB);
    k_gemm_tt<0><<<dim3(KCB / 128, DIM / 64), 512, 0, stream>>>(w2t, H_t, C_t, DIM, KCB);
    k_csq<<<KCB / 256, 256, 0, stream>>>(C_t, csq);
    k_buildB<<<KCB / 64, 256, 0, stream>>>(C_t, Bbf);

    // MFMA distance GEMM + argmin + sum(d)
    k_dist2<<<dim3(KCB / 128, NTOK / 128), 256, 0, stream>>>(Abf, Bbf, zsq, csq, packed, accums);

    k_unpack<<<NTOK / 256, 256, 0, stream>>>(packed, idx, counts);
    k_zqloss<<<BATCH * DIM, 256, 0, stream>>>(z, C_t, idx, out, accums + 1);
    k_scalars<<<1, 256, 0, stream>>>(counts, accums, out + OUTQ);
}

// Round 3
// 639.762 us; speedup vs baseline: 1.8749x; 1.0380x over previous
//
#include <hip/hip_runtime.h>
#include <math.h>

// Problem constants (fixed by setup_inputs)
#define BATCH 2
#define DIM   256
#define THW   8192            // T*H*W = 8*32*32
#define NTOK  16384           // BATCH*THW
#define KCB   8192            // codebook size
#define OUTQ  4194304         // BATCH*DIM*THW
#define K2    768             // split-bf16 concatenated K

typedef short short8 __attribute__((ext_vector_type(8)));
typedef float f32x4 __attribute__((ext_vector_type(4)));

// round-to-nearest-even float -> bf16 bits (no NaN/Inf in this data)
__device__ __forceinline__ unsigned short f2bf_rn(float v) {
    unsigned u = __float_as_uint(v);
    unsigned r = u + 0x7FFFu + ((u >> 16) & 1u);
    return (unsigned short)(r >> 16);
}

// async global->LDS, 16B per lane (lds dest must be wave-uniform base + lane*16)
__device__ __forceinline__ void gl2lds16(const unsigned short* g, unsigned short* l) {
    __builtin_amdgcn_global_load_lds(
        (const __attribute__((address_space(1))) void*)g,
        (__attribute__((address_space(3))) void*)l, 16, 0, 0);
}

// ---------------------------------------------------------------------------
// Build A' [NTOK][768] bf16 = [zhi | zhi | zlo] from z [B][D][THW]; also zsq.
// zsq order-noise is row-constant in d -> argmin-invariant (2% tol on mean_d).
// ---------------------------------------------------------------------------
__global__ void k_buildA(const float* __restrict__ z, unsigned short* __restrict__ A,
                         float* __restrict__ zsq) {
    __shared__ ushort2 tile[64][65];
    __shared__ float zacc[64];
    int t = threadIdx.x;
    int n0 = blockIdx.x * 64;
    int b = n0 >> 13;
    int thw0 = n0 & 8191;
    if (t < 64) zacc[t] = 0.f;
    __syncthreads();
    int nn_r = t & 63, dg = t >> 6;
    for (int dc = 0; dc < 256; dc += 64) {
        for (int r = 0; r < 16; ++r) {
            int dd = r * 4 + dg;
            float v = z[((size_t)(b * 256 + dc + dd)) * 8192 + thw0 + nn_r];
            unsigned short hb = f2bf_rn(v);
            float hf = __uint_as_float((unsigned)hb << 16);
            unsigned short lb = f2bf_rn(v - hf);
            tile[dd][nn_r] = make_ushort2(hb, lb);
            atomicAdd(&zacc[nn_r], v * v);
        }
        __syncthreads();
        int kk = t & 63, ng = t >> 6;
        for (int i2 = 0; i2 < 16; ++i2) {
            int nn = ng + i2 * 4;
            ushort2 hl = tile[kk][nn];
            size_t base = (size_t)(n0 + nn) * K2;
            A[base + dc + kk]       = hl.x;   // zhi
            A[base + 256 + dc + kk] = hl.x;   // zhi (pairs with clo)
            A[base + 512 + dc + kk] = hl.y;   // zlo (pairs with chi)
        }
        __syncthreads();
    }
    if (t < 64) zsq[n0 + t] = zacc[t];
}

// ---------------------------------------------------------------------------
// Build B' [KCB][768] bf16 = [chi | clo | chi] from C_t [D][KCB], fused csq.
// ---------------------------------------------------------------------------
__global__ void k_buildB(const float* __restrict__ C_t, unsigned short* __restrict__ B,
                         float* __restrict__ csq) {
    __shared__ ushort2 tile[64][65];
    __shared__ float kacc[64];
    int t = threadIdx.x;
    int k0 = blockIdx.x * 64;
    if (t < 64) kacc[t] = 0.f;
    __syncthreads();
    int nn_r = t & 63, dg = t >> 6;
    for (int dc = 0; dc < 256; dc += 64) {
        for (int r = 0; r < 16; ++r) {
            int dd = r * 4 + dg;
            float v = C_t[(size_t)(dc + dd) * KCB + k0 + nn_r];
            unsigned short hb = f2bf_rn(v);
            float hf = __uint_as_float((unsigned)hb << 16);
            unsigned short lb = f2bf_rn(v - hf);
            tile[dd][nn_r] = make_ushort2(hb, lb);
            atomicAdd(&kacc[nn_r], v * v);
        }
        __syncthreads();
        int kk = t & 63, ng = t >> 6;
        for (int i2 = 0; i2 < 16; ++i2) {
            int nn = ng + i2 * 4;
            ushort2 hl = tile[kk][nn];
            size_t base = (size_t)(k0 + nn) * K2;
            B[base + dc + kk]       = hl.x;   // chi
            B[base + 256 + dc + kk] = hl.y;   // clo
            B[base + 512 + dc + kk] = hl.x;   // chi
        }
        __syncthreads();
    }
    if (t < 64) csq[k0 + t] = kacc[t];
}

// ---------------------------------------------------------------------------
// Generic 32x32 tile transpose: in [rows][cols] -> out [cols][rows]
// ---------------------------------------------------------------------------
__global__ void k_transpose(const float* __restrict__ in, float* __restrict__ out,
                            int rows, int cols) {
    __shared__ float tile[32][33];
    int tx = threadIdx.x, ty = threadIdx.y;   // 32 x 8
    int x  = blockIdx.x * 32 + tx;
    int y0 = blockIdx.y * 32;
    for (int j = ty; j < 32; j += 8)
        tile[j][tx] = in[(size_t)(y0 + j) * cols + x];
    __syncthreads();
    int x2 = y0 + tx;
    int y2 = blockIdx.x * 32;
    for (int j = ty; j < 32; j += 8)
        out[(size_t)(y2 + j) * rows + x2] = tile[tx][j];
}

// ---------------------------------------------------------------------------
// MLP GEMM (double-acc): Out[m][n] = act(sum_d At[d][m]*Bt[d][n])
// ---------------------------------------------------------------------------
template <int GELU>
__global__ __launch_bounds__(512) void k_gemm_tt(const float* __restrict__ At,
                                                 const float* __restrict__ Bt,
                                                 float* __restrict__ Out,
                                                 int M, int N) {
    __shared__ float As[16][64];
    __shared__ float Bs[16][128];
    int t  = threadIdx.x;
    int ty = t >> 5;
    int tx = t & 31;
    int m0 = blockIdx.y * 64;
    int n0 = blockIdx.x * 128;
    double acc[4][4] = {};
    int dq = t >> 5;
    int lq = t & 31;
    for (int dc = 0; dc < 256; dc += 16) {
        *(float2*)&As[dq][lq * 2] = *(const float2*)&At[(size_t)(dc + dq) * M + m0 + lq * 2];
        *(float4*)&Bs[dq][lq * 4] = *(const float4*)&Bt[(size_t)(dc + dq) * N + n0 + lq * 4];
        __syncthreads();
#pragma unroll
        for (int di = 0; di < 16; ++di) {
            float4 a = *(const float4*)&As[di][ty * 4];
            float4 b = *(const float4*)&Bs[di][tx * 4];
            float av[4] = {a.x, a.y, a.z, a.w};
            float bv[4] = {b.x, b.y, b.z, b.w};
#pragma unroll
            for (int i = 0; i < 4; ++i)
#pragma unroll
                for (int j = 0; j < 4; ++j)
                    acc[i][j] += (double)av[i] * (double)bv[j];
        }
        __syncthreads();
    }
#pragma unroll
    for (int i = 0; i < 4; ++i) {
        float v[4];
#pragma unroll
        for (int j = 0; j < 4; ++j) {
            float h = (float)acc[i][j];
            if (GELU) {
                double x = (double)h;
                h = (float)(x * 0.5 * (1.0 + erf(x * 0.7071067811865475244)));
            }
            v[j] = h;
        }
        *(float4*)&Out[(size_t)(m0 + ty * 4 + i) * N + n0 + tx * 4] =
            make_float4(v[0], v[1], v[2], v[3]);
    }
}

// ---------------------------------------------------------------------------
// Distance GEMM on MFMA: A'[16384][768] x B'[8192][768]^T, 128x128 tiles,
// 4 waves x (4x4) mfma_f32_16x16x32_bf16 frags, global_load_lds staging.
// XOR chunk swizzle: LDS slot (row, ch) holds global chunk ch^(row&7), so
// fragment ds_read_b128 (rows l15, chunk kk*4+quad) spreads all 32 banks.
// Epilogue: d = (zsq+csq) - 2*dot, per-row argmin (lex ties), sum(d).
// LDS = 32 KB exactly (epilogue arrays alias Asm after final barrier).
// ---------------------------------------------------------------------------
__global__ __launch_bounds__(256) void k_dist2(const unsigned short* __restrict__ A,
                                               const unsigned short* __restrict__ B,
                                               const float* __restrict__ zsq,
                                               const float* __restrict__ csq,
                                               unsigned long long* __restrict__ packed,
                                               float* __restrict__ d_sum) {
    __shared__ __align__(16) char smem[32768];
    unsigned short* Asm = (unsigned short*)smem;           // [128][64] bf16
    unsigned short* Bsm = (unsigned short*)(smem + 16384); // [128][64] bf16
    // epilogue aliases (valid only after the last MFMA-loop barrier):
    float* sbd  = (float*)smem;            // [2][128]
    int*   sbk  = (int*)(smem + 1024);     // [2][128]
    float* sred = (float*)(smem + 2048);   // [256]

    int t = threadIdx.x;
    int lane = t & 63;
    int w = t >> 6;
    int wm = w >> 1, wn = w & 1;
    int m0 = blockIdx.y * 128;
    int n0 = blockIdx.x * 128;

    // staging: wave w covers rows w*8+(lane>>3) (+32*i), lane chunk (lane&7).
    // global chunk is XOR-swizzled by row&7 == lane>>3.
    int rA = w * 8 + (lane >> 3);
    int ch_l = lane & 7;
    int ch_g = ch_l ^ (lane >> 3);
    const unsigned short* gA = A + (size_t)(m0 + rA) * K2 + ch_g * 8;
    const unsigned short* gB = B + (size_t)(n0 + rA) * K2 + ch_g * 8;
    unsigned short* lA = &Asm[rA * 64 + ch_l * 8];  // == wave base + lane*16B
    unsigned short* lB = &Bsm[rA * 64 + ch_l * 8];

    f32x4 acc[4][4];
#pragma unroll
    for (int i = 0; i < 4; ++i)
#pragma unroll
        for (int j = 0; j < 4; ++j)
            acc[i][j] = f32x4{0.f, 0.f, 0.f, 0.f};

    // prologue: stage kc=0
#pragma unroll
    for (int i = 0; i < 4; ++i) {
        gl2lds16(gA + (size_t)(32 * i) * K2, lA + 32 * i * 64);
        gl2lds16(gB + (size_t)(32 * i) * K2, lB + 32 * i * 64);
    }
    __syncthreads();

    int l15 = lane & 15;
    int quad = lane >> 4;
    int sw = l15 & 7;                       // row&7 for all fragment rows
    for (int kc = 0; kc < 12; ++kc) {
#pragma unroll
        for (int kk = 0; kk < 2; ++kk) {
            short8 a[4], b[4];
#pragma unroll
            for (int i = 0; i < 4; ++i)
                a[i] = *(const short8*)&Asm[(wm * 64 + i * 16 + l15) * 64 +
                                            (((kk * 4 + quad) ^ sw) * 8)];
#pragma unroll
            for (int j = 0; j < 4; ++j)
                b[j] = *(const short8*)&Bsm[(wn * 64 + j * 16 + l15) * 64 +
                                            (((kk * 4 + quad) ^ sw) * 8)];
#pragma unroll
            for (int i = 0; i < 4; ++i)
#pragma unroll
                for (int j = 0; j < 4; ++j)
                    acc[i][j] = __builtin_amdgcn_mfma_f32_16x16x32_bf16(a[i], b[j], acc[i][j], 0, 0, 0);
        }
        __syncthreads();
        if (kc < 11) {
            int ko = (kc + 1) * 64;
#pragma unroll
            for (int i = 0; i < 4; ++i) {
                gl2lds16(gA + (size_t)(32 * i) * K2 + ko, lA + 32 * i * 64);
                gl2lds16(gB + (size_t)(32 * i) * K2 + ko, lB + 32 * i * 64);
            }
            __syncthreads();
        }
    }

    // epilogue: C/D layout col=lane&15, row=quad*4+reg.  zsq/csq via L1.
    float cv[4];
#pragma unroll
    for (int j = 0; j < 4; ++j)
        cv[j] = csq[n0 + wn * 64 + j * 16 + l15];
    float dsum = 0.f;
#pragma unroll
    for (int i = 0; i < 4; ++i) {
#pragma unroll
        for (int reg = 0; reg < 4; ++reg) {
            int rloc = wm * 64 + i * 16 + quad * 4 + reg;
            float zs = zsq[m0 + rloc];
            float bd = 3.4e38f;
            int   bk = 0x7fffffff;
#pragma unroll
            for (int j = 0; j < 4; ++j) {
                int cloc = wn * 64 + j * 16 + l15;
                float dd = (zs + cv[j]) - 2.0f * acc[i][j][reg];
                dsum += dd;
                int ck = n0 + cloc;
                if (dd < bd || (dd == bd && ck < bk)) { bd = dd; bk = ck; }
            }
#pragma unroll
            for (int off = 1; off < 16; off <<= 1) {
                float od = __shfl_xor(bd, off, 64);
                int   ok = __shfl_xor(bk, off, 64);
                if (od < bd || (od == bd && ok < bk)) { bd = od; bk = ok; }
            }
            if (l15 == 0) { sbd[wn * 128 + rloc] = bd; sbk[wn * 128 + rloc] = bk; }
        }
    }
    sred[t] = dsum;
    __syncthreads();
    for (int s = 128; s > 0; s >>= 1) {
        if (t < s) sred[t] += sred[t + s];
        __syncthreads();
    }
    if (t == 0) atomicAdd(d_sum, sred[0]);
    if (t < 128) {
        float d0 = sbd[t], d1 = sbd[128 + t];
        int   i0 = sbk[t], i1 = sbk[128 + t];
        float bd; int bk;
        if (d1 < d0 || (d1 == d0 && i1 < i0)) { bd = d1; bk = i1; }
        else                                  { bd = d0; bk = i0; }
        unsigned long long p =
            ((unsigned long long)__float_as_uint(bd) << 32) | (unsigned)bk;
        atomicMin(&packed[m0 + t], p);
    }
}

// ---------------------------------------------------------------------------
// Unpack argmin + histogram
// ---------------------------------------------------------------------------
__global__ void k_unpack(const unsigned long long* __restrict__ packed,
                         int* __restrict__ idx, int* __restrict__ counts) {
    int n = blockIdx.x * 256 + threadIdx.x;
    unsigned long long p = packed[n];
    int k = (int)(p & 0xffffffffull);
    idx[n] = k;
    atomicAdd(&counts[k], 1);
}

// ---------------------------------------------------------------------------
// z_q gather (channels-first) + loss partial sums
// ---------------------------------------------------------------------------
__global__ void k_zqloss(const float* __restrict__ z, const float* __restrict__ C_t,
                         const int* __restrict__ idx, float* __restrict__ out,
                         float* __restrict__ loss_sum) {
    __shared__ float red[256];
    int bid = blockIdx.x;
    int b = bid >> 8;
    int d = bid & 255;
    int t = threadIdx.x;
    const float* crow = C_t + (size_t)d * KCB;
    const int* ib = idx + b * THW;
    size_t base = ((size_t)(b * DIM + d)) * THW;
    float lsum = 0.f;
    for (int it = 0; it < 32; ++it) {
        int thw = it * 256 + t;
        int id = ib[thw];
        float v = crow[id];
        float zz = z[base + thw];
        out[base + thw] = v;
        float df = v - zz;
        lsum += df * df;
    }
    red[t] = lsum;
    __syncthreads();
    for (int s = 128; s > 0; s >>= 1) {
        if (t < s) red[t] += red[t + s];
        __syncthreads();
    }
    if (t == 0) atomicAdd(loss_sum, red[0]);
}

// ---------------------------------------------------------------------------
// Final scalars
// ---------------------------------------------------------------------------
__global__ void k_scalars(const int* __restrict__ counts,
                          const float* __restrict__ accums,
                          float* __restrict__ out_tail) {
    __shared__ float red[256];
    int t = threadIdx.x;
    float s = 0.f;
    for (int k = t; k < KCB; k += 256) {
        float e = (float)counts[k] * (1.0f / 16384.0f);
        s += e * logf(e + 1e-10f);
    }
    red[t] = s;
    __syncthreads();
    for (int st = 128; st > 0; st >>= 1) {
        if (t < st) red[t] += red[t + st];
        __syncthreads();
    }
    if (t == 0) {
        out_tail[0] = 1.25f * accums[1] / 4194304.0f;
        out_tail[1] = expf(-red[0]);
        out_tail[2] = accums[0] / (16384.0f * 8192.0f);
    }
}

// ---------------------------------------------------------------------------
extern "C" void kernel_launch(void* const* d_in, const int* in_sizes, int n_in,
                              void* d_out, int out_size, void* d_ws, size_t ws_size,
                              hipStream_t stream) {
    const float* z     = (const float*)d_in[0];   // [2][256][8192]
    const float* emb_w = (const float*)d_in[1];   // [8192][256]
    const float* w1    = (const float*)d_in[2];   // [256][256]
    const float* w2    = (const float*)d_in[3];   // [256][256]
    float* out = (float*)d_out;

    char* w = (char*)d_ws;
    unsigned short* Abf = (unsigned short*)(w + 0);          // 25,165,824 B [16384][768]
    float* R1    = (float*)(w + 25165824);   // emb_t, later aliased by C_t (8,388,608 B)
    float* H_t   = (float*)(w + 33554432);   // 8,388,608 B  [256][8192]
    float* w1t   = (float*)(w + 41943040);   // 262,144 B
    float* w2t   = (float*)(w + 42205184);   // 262,144 B
    float* zsq   = (float*)(w + 42467328);   // 65,536 B
    float* csq   = (float*)(w + 42532864);   // 32,768 B
    unsigned long long* packed = (unsigned long long*)(w + 42565632); // 131,072 B
    int*   idx    = (int*)(w + 42696704);    // 65,536 B
    int*   counts = (int*)(w + 42762240);    // 32,768 B
    float* accums = (float*)(w + 42795008);  // [0]=d_sum [1]=loss_sum

    float* emb_t = R1;
    float* C_t   = R1;                        // alias: emb_t dead after gemm#1
    // B' lives in d_out: dead before k_zqloss overwrites it with z_q
    unsigned short* Bbf = (unsigned short*)d_out;  // 12,582,912 B <= 16 MB

    hipMemsetAsync(counts, 0, 32768 + 8, stream);
    hipMemsetAsync(packed, 0xFF, (size_t)NTOK * 8, stream);

    // A' + zsq straight from z
    k_buildA<<<NTOK / 64, 256, 0, stream>>>(z, Abf, zsq);

    // transposes for the MLP GEMMs
    {
        dim3 blk(32, 8);
        k_transpose<<<dim3(DIM / 32, KCB / 32), blk, 0, stream>>>(emb_w, emb_t, KCB, DIM);
        k_transpose<<<dim3(DIM / 32, DIM / 32), blk, 0, stream>>>(w1, w1t, DIM, DIM);
        k_transpose<<<dim3(DIM / 32, DIM / 32), blk, 0, stream>>>(w2, w2t, DIM, DIM);
    }
    // codebook MLP: H_t = gelu(w1 @ emb^T) ; C_t = w2 @ H^T
    k_gemm_tt<1><<<dim3(KCB / 128, DIM / 64), 512, 0, stream>>>(w1t, emb_t, H_t, DIM, KCB);
    k_gemm_tt<0><<<dim3(KCB / 128, DIM / 64), 512, 0, stream>>>(w2t, H_t, C_t, DIM, KCB);
    // B' + csq fused
    k_buildB<<<KCB / 64, 256, 0, stream>>>(C_t, Bbf, csq);

    // MFMA distance GEMM + argmin + sum(d)
    k_dist2<<<dim3(KCB / 128, NTOK / 128), 256, 0, stream>>>(Abf, Bbf, zsq, csq, packed, accums);

    k_unpack<<<NTOK / 256, 256, 0, stream>>>(packed, idx, counts);
    k_zqloss<<<BATCH * DIM, 256, 0, stream>>>(z, C_t, idx, out, accums + 1);
    k_scalars<<<1, 256, 0, stream>>>(counts, accums, out + OUTQ);
}

// Round 4
// 615.599 us; speedup vs baseline: 1.9484x; 1.0393x over previous
//
#include <hip/hip_runtime.h>
#include <math.h>

// Problem constants (fixed by setup_inputs)
#define BATCH 2
#define DIM   256
#define THW   8192            // T*H*W = 8*32*32
#define NTOK  16384           // BATCH*THW
#define KCB   8192            // codebook size
#define OUTQ  4194304         // BATCH*DIM*THW
#define K2    768             // split-bf16 concatenated K

typedef short short8 __attribute__((ext_vector_type(8)));
typedef float f32x4 __attribute__((ext_vector_type(4)));

// round-to-nearest-even float -> bf16 bits (no NaN/Inf in this data)
__device__ __forceinline__ unsigned short f2bf_rn(float v) {
    unsigned u = __float_as_uint(v);
    unsigned r = u + 0x7FFFu + ((u >> 16) & 1u);
    return (unsigned short)(r >> 16);
}

// async global->LDS, 16B per lane (lds dest must be wave-uniform base + lane*16)
__device__ __forceinline__ void gl2lds16(const unsigned short* g, unsigned short* l) {
    __builtin_amdgcn_global_load_lds(
        (const __attribute__((address_space(1))) void*)g,
        (__attribute__((address_space(3))) void*)l, 16, 0, 0);
}

// ---------------------------------------------------------------------------
// Build A' [NTOK][768] bf16 = [zhi | zhi | zlo] from z [B][D][THW]; also zsq.
// zsq order-noise is row-constant in d -> argmin-invariant (2% tol on mean_d).
// ---------------------------------------------------------------------------
__global__ void k_buildA(const float* __restrict__ z, unsigned short* __restrict__ A,
                         float* __restrict__ zsq) {
    __shared__ ushort2 tile[64][65];
    __shared__ float zacc[64];
    int t = threadIdx.x;
    int n0 = blockIdx.x * 64;
    int b = n0 >> 13;
    int thw0 = n0 & 8191;
    if (t < 64) zacc[t] = 0.f;
    __syncthreads();
    int nn_r = t & 63, dg = t >> 6;
    float lacc = 0.f;
    for (int dc = 0; dc < 256; dc += 64) {
        for (int r = 0; r < 16; ++r) {
            int dd = r * 4 + dg;
            float v = z[((size_t)(b * 256 + dc + dd)) * 8192 + thw0 + nn_r];
            unsigned short hb = f2bf_rn(v);
            float hf = __uint_as_float((unsigned)hb << 16);
            unsigned short lb = f2bf_rn(v - hf);
            tile[dd][nn_r] = make_ushort2(hb, lb);
            lacc += v * v;
        }
        __syncthreads();
        int kk = t & 63, ng = t >> 6;
        for (int i2 = 0; i2 < 16; ++i2) {
            int nn = ng + i2 * 4;
            ushort2 hl = tile[kk][nn];
            size_t base = (size_t)(n0 + nn) * K2;
            A[base + dc + kk]       = hl.x;   // zhi
            A[base + 256 + dc + kk] = hl.x;   // zhi (pairs with clo)
            A[base + 512 + dc + kk] = hl.y;   // zlo (pairs with chi)
        }
        __syncthreads();
    }
    atomicAdd(&zacc[nn_r], lacc);
    __syncthreads();
    if (t < 64) zsq[n0 + t] = zacc[t];
}

// ---------------------------------------------------------------------------
// Build B' [KCB][768] bf16 = [chi | clo | chi] from C_t [D][KCB], fused csq.
// ---------------------------------------------------------------------------
__global__ void k_buildB(const float* __restrict__ C_t, unsigned short* __restrict__ B,
                         float* __restrict__ csq) {
    __shared__ ushort2 tile[64][65];
    __shared__ float kacc[64];
    int t = threadIdx.x;
    int k0 = blockIdx.x * 64;
    if (t < 64) kacc[t] = 0.f;
    __syncthreads();
    int nn_r = t & 63, dg = t >> 6;
    float lacc = 0.f;
    for (int dc = 0; dc < 256; dc += 64) {
        for (int r = 0; r < 16; ++r) {
            int dd = r * 4 + dg;
            float v = C_t[(size_t)(dc + dd) * KCB + k0 + nn_r];
            unsigned short hb = f2bf_rn(v);
            float hf = __uint_as_float((unsigned)hb << 16);
            unsigned short lb = f2bf_rn(v - hf);
            tile[dd][nn_r] = make_ushort2(hb, lb);
            lacc += v * v;
        }
        __syncthreads();
        int kk = t & 63, ng = t >> 6;
        for (int i2 = 0; i2 < 16; ++i2) {
            int nn = ng + i2 * 4;
            ushort2 hl = tile[kk][nn];
            size_t base = (size_t)(k0 + nn) * K2;
            B[base + dc + kk]       = hl.x;   // chi
            B[base + 256 + dc + kk] = hl.y;   // clo
            B[base + 512 + dc + kk] = hl.x;   // chi
        }
        __syncthreads();
    }
    atomicAdd(&kacc[nn_r], lacc);
    __syncthreads();
    if (t < 64) csq[k0 + t] = kacc[t];
}

// ---------------------------------------------------------------------------
// Generic 32x32 tile transpose: in [rows][cols] -> out [cols][rows]
// ---------------------------------------------------------------------------
__global__ void k_transpose(const float* __restrict__ in, float* __restrict__ out,
                            int rows, int cols) {
    __shared__ float tile[32][33];
    int tx = threadIdx.x, ty = threadIdx.y;   // 32 x 8
    int x  = blockIdx.x * 32 + tx;
    int y0 = blockIdx.y * 32;
    for (int j = ty; j < 32; j += 8)
        tile[j][tx] = in[(size_t)(y0 + j) * cols + x];
    __syncthreads();
    int x2 = y0 + tx;
    int y2 = blockIdx.x * 32;
    for (int j = ty; j < 32; j += 8)
        out[(size_t)(y2 + j) * rows + x2] = tile[tx][j];
}

// ---------------------------------------------------------------------------
// MLP GEMM (double-acc): Out[m][n] = act(sum_d At[d][m]*Bt[d][n])
// ---------------------------------------------------------------------------
template <int GELU>
__global__ __launch_bounds__(512) void k_gemm_tt(const float* __restrict__ At,
                                                 const float* __restrict__ Bt,
                                                 float* __restrict__ Out,
                                                 int M, int N) {
    __shared__ float As[16][64];
    __shared__ float Bs[16][128];
    int t  = threadIdx.x;
    int ty = t >> 5;
    int tx = t & 31;
    int m0 = blockIdx.y * 64;
    int n0 = blockIdx.x * 128;
    double acc[4][4] = {};
    int dq = t >> 5;
    int lq = t & 31;
    for (int dc = 0; dc < 256; dc += 16) {
        *(float2*)&As[dq][lq * 2] = *(const float2*)&At[(size_t)(dc + dq) * M + m0 + lq * 2];
        *(float4*)&Bs[dq][lq * 4] = *(const float4*)&Bt[(size_t)(dc + dq) * N + n0 + lq * 4];
        __syncthreads();
#pragma unroll
        for (int di = 0; di < 16; ++di) {
            float4 a = *(const float4*)&As[di][ty * 4];
            float4 b = *(const float4*)&Bs[di][tx * 4];
            float av[4] = {a.x, a.y, a.z, a.w};
            float bv[4] = {b.x, b.y, b.z, b.w};
#pragma unroll
            for (int i = 0; i < 4; ++i)
#pragma unroll
                for (int j = 0; j < 4; ++j)
                    acc[i][j] += (double)av[i] * (double)bv[j];
        }
        __syncthreads();
    }
#pragma unroll
    for (int i = 0; i < 4; ++i) {
        float v[4];
#pragma unroll
        for (int j = 0; j < 4; ++j) {
            float h = (float)acc[i][j];
            if (GELU) {
                double x = (double)h;
                h = (float)(x * 0.5 * (1.0 + erf(x * 0.7071067811865475244)));
            }
            v[j] = h;
        }
        *(float4*)&Out[(size_t)(m0 + ty * 4 + i) * N + n0 + tx * 4] =
            make_float4(v[0], v[1], v[2], v[3]);
    }
}

// ---------------------------------------------------------------------------
// Distance GEMM on MFMA, round 4 structure:
//  - 128x128 tile, 4 waves x (4x4) mfma_f32_16x16x32_bf16
//  - BK=32, DOUBLE-BUFFERED LDS (2 x 8 KB per matrix = 32 KB total):
//    prefetch kc+1 via global_load_lds BEFORE computing kc; ONE barrier/kc
//    (compiler's vmcnt(0) drain lands after a full compute phase)
//  - chunk rotation g=(ch+(row>>1))&3 -> fragment ds_read_b128 is 2-way (free)
//  - XCD-aware swizzle: xcd=lin&7 owns n-tiles [8*xcd,8*xcd+8) swept over m
//    -> per-XCD B' working set 1.5 MB (L2-resident)
// Epilogue: d = (zsq+csq) - 2*dot, per-row lex argmin, sum(d).
// ---------------------------------------------------------------------------
__global__ __launch_bounds__(256) void k_dist2(const unsigned short* __restrict__ A,
                                               const unsigned short* __restrict__ B,
                                               const float* __restrict__ zsq,
                                               const float* __restrict__ csq,
                                               unsigned long long* __restrict__ packed,
                                               float* __restrict__ d_sum) {
    __shared__ __align__(16) char smem[32768];
    unsigned short* bufA = (unsigned short*)smem;           // [2][128][32]
    unsigned short* bufB = (unsigned short*)(smem + 16384); // [2][128][32]
    // epilogue aliases (valid only after the final K-loop barrier):
    float* sbd  = (float*)smem;            // [2][128]
    int*   sbk  = (int*)(smem + 1024);     // [2][128]
    float* sred = (float*)(smem + 2048);   // [256]

    int t = threadIdx.x;
    int lane = t & 63;
    int w = t >> 6;
    int wm = w >> 1, wn = w & 1;

    // XCD-aware decode of 1-D grid (8192 blocks)
    int lin = blockIdx.x;
    int xcd = lin & 7;
    int g   = lin >> 3;
    int n0  = (xcd * 8 + (g & 7)) * 128;
    int m0  = (g >> 3) * 128;

    // staging geometry: round r covers rows r*64 + w*16 + (lane>>2), chunk lane&3.
    // stored chunk ch holds global chunk (ch + ((row>>1)&3)) & 3.
    int srow0 = w * 16 + (lane >> 2);          // round 0 row
    int sch   = lane & 3;
    int g0 = (sch + ((srow0 >> 1) & 3)) & 3;
    int g1 = (sch + (((srow0 + 64) >> 1) & 3)) & 3;
    const unsigned short* gA0 = A + (size_t)(m0 + srow0) * K2 + g0 * 8;
    const unsigned short* gA1 = A + (size_t)(m0 + srow0 + 64) * K2 + g1 * 8;
    const unsigned short* gB0 = B + (size_t)(n0 + srow0) * K2 + g0 * 8;
    const unsigned short* gB1 = B + (size_t)(n0 + srow0 + 64) * K2 + g1 * 8;
    int ld0 = srow0 * 32 + sch * 8;            // ushort offset (== base + lane*16B)
    int ld1 = (srow0 + 64) * 32 + sch * 8;

    f32x4 acc[4][4];
#pragma unroll
    for (int i = 0; i < 4; ++i)
#pragma unroll
        for (int j = 0; j < 4; ++j)
            acc[i][j] = f32x4{0.f, 0.f, 0.f, 0.f};

    // prologue: stage kc=0 into buffer 0
    gl2lds16(gA0, bufA + ld0);
    gl2lds16(gA1, bufA + ld1);
    gl2lds16(gB0, bufB + ld0);
    gl2lds16(gB1, bufB + ld1);
    __syncthreads();

    int l15 = lane & 15;
    int quad = lane >> 4;
    int fch = ((quad - (l15 >> 1)) & 3) * 8;   // rotated chunk for fragment reads

    for (int kc = 0; kc < 24; ++kc) {
        int p = (kc & 1) * 4096;               // current buffer (ushort offset)
        if (kc < 23) {                         // prefetch kc+1 into other buffer
            int q = ((kc + 1) & 1) * 4096;
            int ko = (kc + 1) * 32;
            gl2lds16(gA0 + ko, bufA + q + ld0);
            gl2lds16(gA1 + ko, bufA + q + ld1);
            gl2lds16(gB0 + ko, bufB + q + ld0);
            gl2lds16(gB1 + ko, bufB + q + ld1);
        }
        short8 a[4], b[4];
#pragma unroll
        for (int i = 0; i < 4; ++i)
            a[i] = *(const short8*)&bufA[p + (wm * 64 + i * 16 + l15) * 32 + fch];
#pragma unroll
        for (int j = 0; j < 4; ++j)
            b[j] = *(const short8*)&bufB[p + (wn * 64 + j * 16 + l15) * 32 + fch];
#pragma unroll
        for (int i = 0; i < 4; ++i)
#pragma unroll
            for (int j = 0; j < 4; ++j)
                acc[i][j] = __builtin_amdgcn_mfma_f32_16x16x32_bf16(a[i], b[j], acc[i][j], 0, 0, 0);
        __syncthreads();   // drains this wave's prefetch (vmcnt) + protects buf reuse
    }

    // epilogue: C/D layout col=lane&15, row=quad*4+reg.  zsq/csq via L1.
    float cv[4];
#pragma unroll
    for (int j = 0; j < 4; ++j)
        cv[j] = csq[n0 + wn * 64 + j * 16 + l15];
    float dsum = 0.f;
#pragma unroll
    for (int i = 0; i < 4; ++i) {
#pragma unroll
        for (int reg = 0; reg < 4; ++reg) {
            int rloc = wm * 64 + i * 16 + quad * 4 + reg;
            float zs = zsq[m0 + rloc];
            float bd = 3.4e38f;
            int   bk = 0x7fffffff;
#pragma unroll
            for (int j = 0; j < 4; ++j) {
                int cloc = wn * 64 + j * 16 + l15;
                float dd = (zs + cv[j]) - 2.0f * acc[i][j][reg];
                dsum += dd;
                int ck = n0 + cloc;
                if (dd < bd || (dd == bd && ck < bk)) { bd = dd; bk = ck; }
            }
#pragma unroll
            for (int off = 1; off < 16; off <<= 1) {
                float od = __shfl_xor(bd, off, 64);
                int   ok = __shfl_xor(bk, off, 64);
                if (od < bd || (od == bd && ok < bk)) { bd = od; bk = ok; }
            }
            if (l15 == 0) { sbd[wn * 128 + rloc] = bd; sbk[wn * 128 + rloc] = bk; }
        }
    }
    sred[t] = dsum;
    __syncthreads();
    for (int s = 128; s > 0; s >>= 1) {
        if (t < s) sred[t] += sred[t + s];
        __syncthreads();
    }
    if (t == 0) atomicAdd(d_sum, sred[0]);
    if (t < 128) {
        float d0 = sbd[t], d1 = sbd[128 + t];
        int   i0 = sbk[t], i1 = sbk[128 + t];
        float bd; int bk;
        if (d1 < d0 || (d1 == d0 && i1 < i0)) { bd = d1; bk = i1; }
        else                                  { bd = d0; bk = i0; }
        unsigned long long p =
            ((unsigned long long)__float_as_uint(bd) << 32) | (unsigned)bk;
        atomicMin(&packed[m0 + t], p);
    }
}

// ---------------------------------------------------------------------------
// Unpack argmin + histogram
// ---------------------------------------------------------------------------
__global__ void k_unpack(const unsigned long long* __restrict__ packed,
                         int* __restrict__ idx, int* __restrict__ counts) {
    int n = blockIdx.x * 256 + threadIdx.x;
    unsigned long long p = packed[n];
    int k = (int)(p & 0xffffffffull);
    idx[n] = k;
    atomicAdd(&counts[k], 1);
}

// ---------------------------------------------------------------------------
// z_q gather (channels-first) + loss partial sums
// ---------------------------------------------------------------------------
__global__ void k_zqloss(const float* __restrict__ z, const float* __restrict__ C_t,
                         const int* __restrict__ idx, float* __restrict__ out,
                         float* __restrict__ loss_sum) {
    __shared__ float red[256];
    int bid = blockIdx.x;
    int b = bid >> 8;
    int d = bid & 255;
    int t = threadIdx.x;
    const float* crow = C_t + (size_t)d * KCB;
    const int* ib = idx + b * THW;
    size_t base = ((size_t)(b * DIM + d)) * THW;
    float lsum = 0.f;
    for (int it = 0; it < 32; ++it) {
        int thw = it * 256 + t;
        int id = ib[thw];
        float v = crow[id];
        float zz = z[base + thw];
        out[base + thw] = v;
        float df = v - zz;
        lsum += df * df;
    }
    red[t] = lsum;
    __syncthreads();
    for (int s = 128; s > 0; s >>= 1) {
        if (t < s) red[t] += red[t + s];
        __syncthreads();
    }
    if (t == 0) atomicAdd(loss_sum, red[0]);
}

// ---------------------------------------------------------------------------
// Final scalars
// ---------------------------------------------------------------------------
__global__ void k_scalars(const int* __restrict__ counts,
                          const float* __restrict__ accums,
                          float* __restrict__ out_tail) {
    __shared__ float red[256];
    int t = threadIdx.x;
    float s = 0.f;
    for (int k = t; k < KCB; k += 256) {
        float e = (float)counts[k] * (1.0f / 16384.0f);
        s += e * logf(e + 1e-10f);
    }
    red[t] = s;
    __syncthreads();
    for (int st = 128; st > 0; st >>= 1) {
        if (t < st) red[t] += red[t + st];
        __syncthreads();
    }
    if (t == 0) {
        out_tail[0] = 1.25f * accums[1] / 4194304.0f;
        out_tail[1] = expf(-red[0]);
        out_tail[2] = accums[0] / (16384.0f * 8192.0f);
    }
}

// ---------------------------------------------------------------------------
extern "C" void kernel_launch(void* const* d_in, const int* in_sizes, int n_in,
                              void* d_out, int out_size, void* d_ws, size_t ws_size,
                              hipStream_t stream) {
    const float* z     = (const float*)d_in[0];   // [2][256][8192]
    const float* emb_w = (const float*)d_in[1];   // [8192][256]
    const float* w1    = (const float*)d_in[2];   // [256][256]
    const float* w2    = (const float*)d_in[3];   // [256][256]
    float* out = (float*)d_out;

    char* w = (char*)d_ws;
    unsigned short* Abf = (unsigned short*)(w + 0);          // 25,165,824 B [16384][768]
    float* R1    = (float*)(w + 25165824);   // emb_t, later aliased by C_t (8,388,608 B)
    float* H_t   = (float*)(w + 33554432);   // 8,388,608 B  [256][8192]
    float* w1t   = (float*)(w + 41943040);   // 262,144 B
    float* w2t   = (float*)(w + 42205184);   // 262,144 B
    float* zsq   = (float*)(w + 42467328);   // 65,536 B
    float* csq   = (float*)(w + 42532864);   // 32,768 B
    unsigned long long* packed = (unsigned long long*)(w + 42565632); // 131,072 B
    int*   idx    = (int*)(w + 42696704);    // 65,536 B
    int*   counts = (int*)(w + 42762240);    // 32,768 B
    float* accums = (float*)(w + 42795008);  // [0]=d_sum [1]=loss_sum

    float* emb_t = R1;
    float* C_t   = R1;                        // alias: emb_t dead after gemm#1
    // B' lives in d_out: dead before k_zqloss overwrites it with z_q
    unsigned short* Bbf = (unsigned short*)d_out;  // 12,582,912 B <= 16 MB

    hipMemsetAsync(counts, 0, 32768 + 8, stream);
    hipMemsetAsync(packed, 0xFF, (size_t)NTOK * 8, stream);

    // A' + zsq straight from z
    k_buildA<<<NTOK / 64, 256, 0, stream>>>(z, Abf, zsq);

    // transposes for the MLP GEMMs
    {
        dim3 blk(32, 8);
        k_transpose<<<dim3(DIM / 32, KCB / 32), blk, 0, stream>>>(emb_w, emb_t, KCB, DIM);
        k_transpose<<<dim3(DIM / 32, DIM / 32), blk, 0, stream>>>(w1, w1t, DIM, DIM);
        k_transpose<<<dim3(DIM / 32, DIM / 32), blk, 0, stream>>>(w2, w2t, DIM, DIM);
    }
    // codebook MLP: H_t = gelu(w1 @ emb^T) ; C_t = w2 @ H^T
    k_gemm_tt<1><<<dim3(KCB / 128, DIM / 64), 512, 0, stream>>>(w1t, emb_t, H_t, DIM, KCB);
    k_gemm_tt<0><<<dim3(KCB / 128, DIM / 64), 512, 0, stream>>>(w2t, H_t, C_t, DIM, KCB);
    // B' + csq fused
    k_buildB<<<KCB / 64, 256, 0, stream>>>(C_t, Bbf, csq);

    // MFMA distance GEMM + argmin + sum(d)  (1-D grid, XCD swizzle inside)
    k_dist2<<<8192, 256, 0, stream>>>(Abf, Bbf, zsq, csq, packed, accums);

    k_unpack<<<NTOK / 256, 256, 0, stream>>>(packed, idx, counts);
    k_zqloss<<<BATCH * DIM, 256, 0, stream>>>(z, C_t, idx, out, accums + 1);
    k_scalars<<<1, 256, 0, stream>>>(counts, accums, out + OUTQ);
}